// Round 8
// baseline (2033.688 us; speedup 1.0000x reference)
//
#include <hip/hip_runtime.h>

typedef __bf16 bf16;
typedef __attribute__((ext_vector_type(8))) __bf16 bf16x8;
typedef __attribute__((ext_vector_type(4))) float f32x4;
typedef __attribute__((ext_vector_type(2))) float f32x2;
typedef unsigned int u32;

// ---------------------------------------------------------------------------
// GraphMatchNet: 3x { decomposed message GEMM (bf16 MFMA), dual MFMA flash
// attn (32-key dbuf pipeline, split-K x4, XCD-colocated), GRU (batched GEMM) }
// ---------------------------------------------------------------------------

__global__ void k_gather(const float* __restrict__ emb, const int* __restrict__ x,
                         float* __restrict__ h) {
  int v = blockIdx.x, d = threadIdx.x;
  h[v * 256 + d] = emb[(size_t)x[v] * 256 + d];
}

__global__ void k_edgeproj(const float* __restrict__ ee, const float* __restrict__ Wm,
                           float* __restrict__ P) {
  __shared__ float row[256];
  int a = blockIdx.x, o = threadIdx.x;
  row[o] = ee[a * 256 + o];
  __syncthreads();
  float s = 0.f;
#pragma unroll 8
  for (int k = 0; k < 256; k++) s += row[k] * Wm[o * 768 + 512 + k];
  P[a * 256 + o] = s;
}

__global__ void k_count(const int* __restrict__ ei, const int* __restrict__ ea,
                        unsigned* __restrict__ cnt, unsigned* __restrict__ deg, int E) {
  int e = blockIdx.x * 256 + threadIdx.x;
  if (e >= E) return;
  int dst = ei[E + e];
  atomicAdd(&cnt[dst * 16 + ea[e]], 1u);
  atomicAdd(&deg[dst], 1u);
}

__global__ void k_scan(const unsigned* __restrict__ deg, unsigned* __restrict__ off,
                       unsigned* __restrict__ cur, int N) {
  __shared__ unsigned part[256];
  int tid = threadIdx.x;
  int per = N >> 8;
  unsigned s = 0;
  for (int i = 0; i < per; i++) s += deg[tid * per + i];
  part[tid] = s;
  __syncthreads();
  if (tid == 0) {
    unsigned run = 0;
    for (int i = 0; i < 256; i++) { unsigned t = part[i]; part[i] = run; run += t; }
  }
  __syncthreads();
  unsigned run = part[tid];
  for (int i = 0; i < per; i++) {
    unsigned dv = deg[tid * per + i];
    off[tid * per + i] = run;
    cur[tid * per + i] = run;
    run += dv;
  }
  if (tid == 255) off[N] = run;
}

__global__ void k_fill(const int* __restrict__ ei, unsigned* __restrict__ cur,
                       int* __restrict__ csr, int E) {
  int e = blockIdx.x * 256 + threadIdx.x;
  if (e >= E) return;
  int dst = ei[E + e];
  unsigned pos = atomicAdd(&cur[dst], 1u);
  csr[pos] = ei[e];  // src
}

__global__ void k_cconst(const unsigned* __restrict__ cnt, const unsigned* __restrict__ deg,
                         const float* __restrict__ P, const float* __restrict__ bm,
                         float* __restrict__ C) {
  int v = blockIdx.x, o = threadIdx.x;
  float s = (float)deg[v] * bm[o];
#pragma unroll
  for (int a = 0; a < 16; a++) s += (float)cnt[v * 16 + a] * P[a * 256 + o];
  C[v * 256 + o] = s;
}

__global__ void k_packw(const float* __restrict__ src, bf16* __restrict__ dst,
                        int srcStride, int K) {
  int o = blockIdx.x;
  for (int k = threadIdx.x; k < K; k += 256)
    dst[(size_t)o * K + k] = (bf16)src[(size_t)o * srcStride + k];
}

// both graphs: A0b[v] = [ bf16(deg*h[v]) | bf16(sum_{src} h[src]) ]
__global__ void k_aggA0(const float* __restrict__ h1, const float* __restrict__ h2,
                        const int* __restrict__ csr1, const int* __restrict__ csr2,
                        const unsigned* __restrict__ off1, const unsigned* __restrict__ off2,
                        bf16* __restrict__ A0b1, bf16* __restrict__ A0b2) {
  int gsel = blockIdx.y;
  const float* h = gsel ? h2 : h1;
  const int* csr = gsel ? csr2 : csr1;
  const unsigned* off = gsel ? off2 : off1;
  bf16* A0b = gsel ? A0b2 : A0b1;
  int v = blockIdx.x, d = threadIdx.x;
  unsigned i0 = off[v], i1 = off[v + 1];
  float s = 0.f;
  for (unsigned i = i0; i < i1; i++) s += h[csr[i] * 256 + d];
  A0b[(size_t)v * 512 + 256 + d] = (bf16)s;
  A0b[(size_t)v * 512 + d] = (bf16)(h[v * 256 + d] * (float)(i1 - i0));
}

// both graphs: h (f32) -> hb (bf16 [N][256]) and hbt (bf16 [256][N])
__global__ void k_cvt(const float* __restrict__ h1, const float* __restrict__ h2,
                      bf16* __restrict__ hb1, bf16* __restrict__ hb2,
                      bf16* __restrict__ hbt1, bf16* __restrict__ hbt2, int N) {
  __shared__ bf16 t[64][68];
  int gsel = blockIdx.z;
  const float* h = gsel ? h2 : h1;
  bf16* hb = gsel ? hb2 : hb1;
  bf16* hbt = gsel ? hbt2 : hbt1;
  int v0 = blockIdx.x * 64, d0 = blockIdx.y * 64;
  int tid = threadIdx.x;
#pragma unroll
  for (int i = 0; i < 4; i++) {
    int e = tid + i * 1024;
    int r = e >> 6, c = e & 63;
    bf16 b = (bf16)h[(size_t)(v0 + r) * 256 + d0 + c];
    hb[(size_t)(v0 + r) * 256 + d0 + c] = b;
    t[r][c] = b;
  }
  __syncthreads();
#pragma unroll
  for (int i = 0; i < 4; i++) {
    int e = tid + i * 1024;
    int dr = e >> 6, vc = e & 63;
    hbt[(size_t)(d0 + dr) * N + v0 + vc] = t[vc][dr];
  }
}

__device__ __forceinline__ void gl2lds16(const bf16* g, bf16* l) {
  __builtin_amdgcn_global_load_lds(
      (const __attribute__((address_space(1))) u32*)(const void*)g,
      (__attribute__((address_space(3))) u32*)(void*)l, 16, 0, 0);
}

// ---------------------------------------------------------------------------
// bf16 MFMA GEMM core (128x128 tile, BK=64, dbuf gl2lds staging).
// ---------------------------------------------------------------------------
template <int MODE>  // 0: +=Cmat, bf16 out stride 512 ; 1: +=bias, f32 out
__device__ __forceinline__ void gemm_body(
    const bf16* __restrict__ A, int sA, const bf16* __restrict__ W,
    const float* __restrict__ biasC, float* __restrict__ outf,
    bf16* __restrict__ outb, int sOut, int K, bf16* lds) {
  int tid = threadIdx.x;
  int w = tid >> 6, l = tid & 63;
  int lane15 = l & 15, g = l >> 4;
  int wr = w >> 1, wc = w & 1;
  int row0 = blockIdx.x * 128, col0 = blockIdx.y * 128;

  const bf16* Abase = A + (size_t)row0 * sA;
  const bf16* Wbase = W + (size_t)col0 * K;
  const int HB = 128 * 64;  // elements per half (A or B) per buffer

  auto stage = [&](int buf, int kt) {
#pragma unroll
    for (int i = 0; i < 4; i++) {
      int c = w * 256 + i * 64 + l;
      int r = c >> 3, c8 = c & 7;
      int sc8 = c8 ^ (r & 7);
      gl2lds16(Abase + (size_t)r * sA + kt + sc8 * 8,
               lds + buf * 2 * HB + (w * 256 + i * 64) * 8);
      gl2lds16(Wbase + (size_t)r * K + kt + sc8 * 8,
               lds + buf * 2 * HB + HB + (w * 256 + i * 64) * 8);
    }
  };

  f32x4 acc[4][4];
#pragma unroll
  for (int a = 0; a < 4; a++)
#pragma unroll
    for (int b = 0; b < 4; b++) acc[a][b] = (f32x4){0.f, 0.f, 0.f, 0.f};

  stage(0, 0);
  __syncthreads();
  int nk = K >> 6;
  for (int t = 0; t < nk; t++) {
    int buf = t & 1;
    if (t + 1 < nk) stage(buf ^ 1, (t + 1) << 6);
    const bf16* La = lds + buf * 2 * HB;
    const bf16* Lb = La + HB;
    bf16x8 af[4][2], bfr[4][2];
#pragma unroll
    for (int mt = 0; mt < 4; mt++) {
      int r = wr * 64 + mt * 16 + lane15;
#pragma unroll
      for (int kk = 0; kk < 2; kk++)
        af[mt][kk] = *(const bf16x8*)(La + r * 64 + (((kk * 4 + g) ^ (r & 7)) * 8));
    }
#pragma unroll
    for (int nt = 0; nt < 4; nt++) {
      int cl = wc * 64 + nt * 16 + lane15;
#pragma unroll
      for (int kk = 0; kk < 2; kk++)
        bfr[nt][kk] = *(const bf16x8*)(Lb + cl * 64 + (((kk * 4 + g) ^ (cl & 7)) * 8));
    }
#pragma unroll
    for (int kk = 0; kk < 2; kk++)
#pragma unroll
      for (int mt = 0; mt < 4; mt++)
#pragma unroll
        for (int nt = 0; nt < 4; nt++)
          acc[mt][nt] =
              __builtin_amdgcn_mfma_f32_16x16x32_bf16(af[mt][kk], bfr[nt][kk], acc[mt][nt], 0, 0, 0);
    __syncthreads();
  }
#pragma unroll
  for (int mt = 0; mt < 4; mt++)
#pragma unroll
    for (int nt = 0; nt < 4; nt++) {
      int col = col0 + wc * 64 + nt * 16 + lane15;
#pragma unroll
      for (int r = 0; r < 4; r++) {
        int row = row0 + wr * 64 + mt * 16 + g * 4 + r;
        float v = acc[mt][nt][r];
        if (MODE == 0)
          outb[(size_t)row * 512 + col] = (bf16)(v + biasC[(size_t)row * 256 + col]);
        else
          outf[(size_t)row * sOut + col] = v + biasC[col];
      }
    }
}

// message GEMM, both graphs (blockIdx.z)
__global__ __launch_bounds__(256, 2) void k_gemmM(
    const bf16* __restrict__ A0b1, const bf16* __restrict__ A0b2,
    const bf16* __restrict__ Wmb, const float* __restrict__ C1,
    const float* __restrict__ C2, bf16* __restrict__ A1b1, bf16* __restrict__ A1b2) {
  __shared__ bf16 lds[2 * 2 * 128 * 64];
  int z = blockIdx.z;
  gemm_body<0>(z ? A0b2 : A0b1, 512, Wmb, z ? C2 : C1, nullptr,
               z ? A1b2 : A1b1, 0, 512, lds);
}

// gate GEMMs: z = graph*2 + (0:GI / 1:GH), both graphs in one launch
__global__ __launch_bounds__(256, 2) void k_gemmG(
    const bf16* __restrict__ A1b1, const bf16* __restrict__ A1b2,
    const bf16* __restrict__ hb1, const bf16* __restrict__ hb2,
    const bf16* __restrict__ Wihb, const bf16* __restrict__ Whhb,
    const float* __restrict__ bih, const float* __restrict__ bhh,
    float* __restrict__ big, int N) {
  __shared__ bf16 lds[2 * 2 * 128 * 64];
  int z = blockIdx.z;
  int graph = z >> 1, mat = z & 1;
  const bf16* A = mat ? (graph ? hb2 : hb1) : (graph ? A1b2 : A1b1);
  float* out = big + (size_t)z * N * 768;
  gemm_body<1>(A, mat ? 256 : 512, mat ? Whhb : Wihb, mat ? bhh : bih,
               out, nullptr, 768, mat ? 256 : 512, lds);
}

// ---------------------------------------------------------------------------
// MFMA flash attention v6: 32-key tiles, DOUBLE-BUFFERED (72 KB LDS, still
// 2 blocks/CU). Per tile: issue K(t+1) gl2lds + Vt(t+1) reg-loads BEFORE
// computing tile t; ds_write Vt(t+1) after PV (T14 split); 1 barrier/iter.
// Vt rows padded to 40 bf16 (80 B): 16B-aligned, 20-bank stride -> <=2-way
// conflicts. split-K x4, XCD-colocated (slice = lid%8), NT streaming Q/O.
// ---------------------------------------------------------------------------
__global__ __launch_bounds__(256, 2) void k_flash_mfma(
    const bf16* __restrict__ hb1, const bf16* __restrict__ hbt1,
    const bf16* __restrict__ hb2, const bf16* __restrict__ hbt2,
    float* __restrict__ Opart, float* __restrict__ ml, int N) {
  int lid = blockIdx.x;
  int slice = lid & 7;          // -> XCD (round-robin dispatch)
  int xq = lid >> 3;            // Q-tile index
  int dir = slice & 1, quar = slice >> 1;
  const bf16 *Q, *K, *Kt;
  if (dir == 0) { Q = hb1; K = hb2; Kt = hbt2; }
  else          { Q = hb2; K = hb1; Kt = hbt1; }
  int idx = dir * 4 + quar;
  float* Out = Opart + (size_t)idx * N * 256;
  float* mlp = ml + (size_t)idx * N * 2;

  __shared__ bf16 Klds[2][32 * 256];   // 2 x 16 KB
  __shared__ bf16 Vlds[2][256 * 40];   // 2 x 20 KB (padded rows)
  int tid = threadIdx.x;
  int w = tid >> 6, l = tid & 63;
  int lane15 = l & 15, g = l >> 4;
  int row0 = xq * 128 + w * 32;

  // Q fragments (streaming: non-temporal)
  bf16x8 qf[2][8];
#pragma unroll
  for (int st = 0; st < 2; st++) {
    const bf16* qp = Q + (size_t)(row0 + st * 16 + lane15) * 256 + g * 8;
#pragma unroll
    for (int kk = 0; kk < 8; kk++)
      qf[st][kk] = __builtin_nontemporal_load((bf16x8*)(void*)(qp + kk * 32));
  }
  f32x4 Oacc[2][16];
#pragma unroll
  for (int st = 0; st < 2; st++)
#pragma unroll
    for (int i = 0; i < 16; i++) Oacc[st][i] = (f32x4){0.f, 0.f, 0.f, 0.f};
  float m_run[2] = {-1e30f, -1e30f}, l_run[2] = {0.f, 0.f};

  int qN = N >> 2;
  int kt0 = quar * qN;
  int ntl = qN >> 5;   // 32-key tiles

  // K tile: 32 keys x 512B rows = 1024 x 16B chunks; linear LDS dest,
  // source 16B-slot pre-swizzled (sl ^ key&7) -- same row layout as before.
  auto stageK = [&](int buf, int kt) {
#pragma unroll
    for (int i = 0; i < 4; i++) {
      int c0 = i * 256 + w * 64;
      int c = c0 + l;
      int key = c >> 5, sl = c & 31;
      gl2lds16(K + (size_t)(kt + key) * 256 + ((sl ^ (key & 7)) * 8),
               &Klds[buf][0] + (size_t)c0 * 8);
    }
  };
  // Vt tile: 256 d-rows x 32 keys, key-permuted granules (8B = 4 keys):
  // granule j of row d <- keys (j&1)*16 + (j>>1)*4 + 0..3  (perm pos 4j..4j+3)
  auto loadV = [&](int kt, f32x2* vr) {
#pragma unroll
    for (int i = 0; i < 8; i++) {
      int c = tid + i * 256;
      int d = c >> 3, j = c & 7;
      vr[i] = *(const f32x2*)(const void*)(Kt + (size_t)d * N + kt + (j & 1) * 16 + (j >> 1) * 4);
    }
  };
  auto writeV = [&](int buf, const f32x2* vr) {
#pragma unroll
    for (int i = 0; i < 8; i++) {
      int c = tid + i * 256;
      int d = c >> 3, j = c & 7;
      *(f32x2*)(void*)(&Vlds[buf][0] + (size_t)d * 40 + j * 4) = vr[i];
    }
  };

  {
    f32x2 vr[8];
    stageK(0, kt0);
    loadV(kt0, vr);
    writeV(0, vr);
  }
  __syncthreads();

  for (int t = 0; t < ntl; t++) {
    int buf = t & 1;
    f32x2 vr2[8];
    if (t + 1 < ntl) {
      stageK(buf ^ 1, kt0 + (t + 1) * 32);         // async -> other buffer
      loadV(kt0 + (t + 1) * 32, vr2);              // issue global loads early
    }
    // QK^T (swapped): Sacc[st][nt][r] = S^T[key=nt*16+4g+r][q=row0+st*16+lane15]
    f32x4 Sacc[2][2];
#pragma unroll
    for (int st = 0; st < 2; st++)
#pragma unroll
      for (int i = 0; i < 2; i++) Sacc[st][i] = (f32x4){0.f, 0.f, 0.f, 0.f};
#pragma unroll
    for (int kk = 0; kk < 8; kk++) {
#pragma unroll
      for (int nt = 0; nt < 2; nt++) {
        int key = nt * 16 + lane15;
        int slot = (kk * 4 + g) ^ (key & 7);
        bf16x8 kf = *(const bf16x8*)(&Klds[buf][0] + key * 256 + slot * 8);
        Sacc[0][nt] = __builtin_amdgcn_mfma_f32_16x16x32_bf16(kf, qf[0][kk], Sacc[0][nt], 0, 0, 0);
        Sacc[1][nt] = __builtin_amdgcn_mfma_f32_16x16x32_bf16(kf, qf[1][kk], Sacc[1][nt], 0, 0, 0);
      }
    }
    // online softmax per strip (8 lane-local vals, xor over lane bits 4,5)
    bf16x8 pbs[2];
#pragma unroll
    for (int st = 0; st < 2; st++) {
      float tmax = -1e30f;
#pragma unroll
      for (int nt = 0; nt < 2; nt++)
#pragma unroll
        for (int r = 0; r < 4; r++) tmax = fmaxf(tmax, Sacc[st][nt][r]);
      tmax = fmaxf(tmax, __shfl_xor(tmax, 16));
      tmax = fmaxf(tmax, __shfl_xor(tmax, 32));
      float m_new = fmaxf(m_run[st], tmax);
      float alpha = __expf(m_run[st] - m_new);
      float ts = 0.f;
#pragma unroll
      for (int nt = 0; nt < 2; nt++)
#pragma unroll
        for (int r = 0; r < 4; r++) {
          float p = __expf(Sacc[st][nt][r] - m_new);
          Sacc[st][nt][r] = p;
          ts += p;
        }
      ts += __shfl_xor(ts, 16);
      ts += __shfl_xor(ts, 32);
      bool stable = __all(m_new == m_run[st]);
      if (!stable) {
#pragma unroll
        for (int mt = 0; mt < 16; mt++)
#pragma unroll
          for (int r = 0; r < 4; r++) Oacc[st][mt][r] *= alpha;
      }
      l_run[st] = l_run[st] * alpha + ts;
      m_run[st] = m_new;
      // P fragment == Sacc layout under the key-permuted Vt (pos=g*8+i)
#pragma unroll
      for (int r = 0; r < 4; r++) {
        pbs[st][r] = (bf16)Sacc[st][0][r];
        pbs[st][4 + r] = (bf16)Sacc[st][1][r];
      }
    }
    // PV: O^T += Vt_frag * P_frag; each vf read feeds both strips
#pragma unroll
    for (int mt = 0; mt < 16; mt++) {
      int d = mt * 16 + lane15;
      bf16x8 vf = *(const bf16x8*)(&Vlds[buf][0] + (size_t)d * 40 + g * 8);
      Oacc[0][mt] = __builtin_amdgcn_mfma_f32_16x16x32_bf16(vf, pbs[0], Oacc[0][mt], 0, 0, 0);
      Oacc[1][mt] = __builtin_amdgcn_mfma_f32_16x16x32_bf16(vf, pbs[1], Oacc[1][mt], 0, 0, 0);
    }
    if (t + 1 < ntl) writeV(buf ^ 1, vr2);         // waits its own loads only
    __syncthreads();
  }
#pragma unroll
  for (int st = 0; st < 2; st++) {
    int row = row0 + st * 16 + lane15;
    float* orow = Out + (size_t)row * 256 + g * 4;
#pragma unroll
    for (int mt = 0; mt < 16; mt++) {
      __builtin_nontemporal_store(Oacc[st][mt], (f32x4*)(orow + mt * 16));
    }
    if (g == 0) {
      f32x2 mv = {m_run[st], l_run[st]};
      __builtin_nontemporal_store(mv, (f32x2*)(mlp + row * 2));
    }
  }
}

// merge the four key-quarters; A1b[row][256+d] = bf16(h - att), both graphs
__global__ void k_comb(const float* __restrict__ Opart, const float* __restrict__ ml,
                       const bf16* __restrict__ hb1, const bf16* __restrict__ hb2,
                       bf16* __restrict__ A1b1, bf16* __restrict__ A1b2, int N) {
  int gsel = blockIdx.y;
  const float* Ob = Opart + (size_t)(gsel * 4) * N * 256;
  const float* mlb = ml + (size_t)(gsel * 4) * N * 2;
  const bf16* hb = gsel ? hb2 : hb1;
  bf16* A1b = gsel ? A1b2 : A1b1;
  int row = blockIdx.x, d = threadIdx.x;
  float mx[4], ls[4];
  float m = -1e30f;
#pragma unroll
  for (int q = 0; q < 4; q++) {
    mx[q] = mlb[(size_t)q * N * 2 + row * 2];
    ls[q] = mlb[(size_t)q * N * 2 + row * 2 + 1];
    m = fmaxf(m, mx[q]);
  }
  float denom = 0.f, o = 0.f;
#pragma unroll
  for (int q = 0; q < 4; q++) {
    float a = __expf(mx[q] - m);
    denom += ls[q] * a;
    o += __builtin_nontemporal_load((float*)&Ob[(size_t)q * N * 256 + (size_t)row * 256 + d]) * a;
  }
  o /= denom;
  float hv = (float)hb[(size_t)row * 256 + d];
  A1b[(size_t)row * 512 + 256 + d] = (bf16)(hv - o);
}

// GRU update for both graphs; gi/gh laid out in big[(graph*2 + 0/1)*N*768]
__global__ void k_gru2(float* __restrict__ h1, float* __restrict__ h2,
                       const float* __restrict__ big, int N) {
  int b = blockIdx.x;
  int graph = b >= N;
  int v = graph ? b - N : b;
  int d = threadIdx.x;
  float* h = graph ? h2 : h1;
  const float* gi = big + (size_t)(graph * 2) * N * 768;
  const float* gh = gi + (size_t)N * 768;
  float gir = gi[v * 768 + d], giz = gi[v * 768 + 256 + d], gin = gi[v * 768 + 512 + d];
  float ghr = gh[v * 768 + d], ghz = gh[v * 768 + 256 + d], ghn = gh[v * 768 + 512 + d];
  float r = 1.f / (1.f + __expf(-(gir + ghr)));
  float z = 1.f / (1.f + __expf(-(giz + ghz)));
  float n = tanhf(gin + r * ghn);
  h[v * 256 + d] = (1.f - z) * n + z * h[v * 256 + d];
}

__global__ void k_gate(const float* __restrict__ h1, const float* __restrict__ h2,
                       const float* __restrict__ Wg, const float* __restrict__ bg,
                       float* __restrict__ gbuf, int N) {
  int gsel = blockIdx.y;
  const float* h = gsel ? h2 : h1;
  float* g = gbuf + (size_t)gsel * N;
  int wave = threadIdx.x >> 6, lane = threadIdx.x & 63;
  int v = blockIdx.x * 4 + wave;
  float s = 0.f;
#pragma unroll
  for (int k = lane; k < 256; k += 64) s += h[v * 256 + k] * Wg[k];
#pragma unroll
  for (int sh = 32; sh > 0; sh >>= 1) s += __shfl_xor(s, sh);
  if (lane == 0) g[v] = 1.f / (1.f + __expf(-(s + bg[0])));
}

__global__ void k_poolstats(const float* __restrict__ gbuf, float* __restrict__ stats, int N) {
  __shared__ float red[256];
  int gsel = blockIdx.x;
  const float* g = gbuf + (size_t)gsel * N;
  int tid = threadIdx.x;
  float mx = -1e30f;
  for (int i = tid; i < N; i += 256) mx = fmaxf(mx, g[i]);
  red[tid] = mx;
  __syncthreads();
  for (int s = 128; s > 0; s >>= 1) {
    if (tid < s) red[tid] = fmaxf(red[tid], red[tid + s]);
    __syncthreads();
  }
  float M = red[0];
  __syncthreads();
  float sm = 0.f;
  for (int i = tid; i < N; i += 256) sm += __expf(g[i] - M);
  red[tid] = sm;
  __syncthreads();
  for (int s = 128; s > 0; s >>= 1) {
    if (tid < s) red[tid] += red[tid + s];
    __syncthreads();
  }
  if (tid == 0) { stats[gsel * 2] = M; stats[gsel * 2 + 1] = red[0]; }
}

__global__ void k_poolpart(const float* __restrict__ gbuf, const float* __restrict__ h1,
                           const float* __restrict__ h2, const float* __restrict__ stats,
                           float* __restrict__ part, int N) {
  int gsel = blockIdx.y;
  const float* g = gbuf + (size_t)gsel * N;
  const float* h = gsel ? h2 : h1;
  float* p = part + (size_t)gsel * 32 * 256;
  int c = blockIdx.x, o = threadIdx.x;
  int per = N / 32;
  float M = stats[gsel * 2];
  float s = 0.f;
  for (int v = c * per; v < (c + 1) * per; v++) s += __expf(g[v] - M) * h[v * 256 + o];
  p[c * 256 + o] = s;
}

__global__ void k_poolfin(const float* __restrict__ part, const float* __restrict__ stats,
                          float* __restrict__ out) {
  int gsel = blockIdx.x;
  const float* p = part + (size_t)gsel * 32 * 256;
  int o = threadIdx.x;
  float s = 0.f;
#pragma unroll
  for (int c = 0; c < 32; c++) s += p[c * 256 + o];
  out[gsel * 256 + o] = s / stats[gsel * 2 + 1];
}

extern "C" void kernel_launch(void* const* d_in, const int* in_sizes, int n_in,
                              void* d_out, int out_size, void* d_ws, size_t ws_size,
                              hipStream_t stream) {
  const int* x1 = (const int*)d_in[0];
  const int* x2 = (const int*)d_in[1];
  const int* ei1 = (const int*)d_in[2];
  const int* ei2 = (const int*)d_in[3];
  const int* ea1 = (const int*)d_in[4];
  const int* ea2 = (const int*)d_in[5];
  const float* embed = (const float*)d_in[6];
  const float* eemb = (const float*)d_in[7];
  const float* Wm = (const float*)d_in[8];
  const float* bm = (const float*)d_in[9];
  const float* Wih = (const float*)d_in[10];
  const float* Whh = (const float*)d_in[11];
  const float* bih = (const float*)d_in[12];
  const float* bhh = (const float*)d_in[13];
  const float* Wg = (const float*)d_in[14];
  const float* bg = (const float*)d_in[15];
  const int N = in_sizes[0];   // 8192
  const int E = in_sizes[4];   // 131072
  float* out = (float*)d_out;

  char* ws = (char*)d_ws;
  size_t ofs = 0;
  auto alloc = [&](size_t bytes) -> void* {
    void* p = ws + ofs;
    ofs = (ofs + bytes + 255) & ~(size_t)255;
    return p;
  };
  size_t ND4 = (size_t)N * 256 * 4;
  size_t ND2 = (size_t)N * 256 * 2;
  float* h1 = (float*)alloc(ND4);
  float* h2 = (float*)alloc(ND4);
  float* C1 = (float*)alloc(ND4);
  float* C2 = (float*)alloc(ND4);
  // big region: gi1|gh1|gi2|gh2 (4 * N*768 f32 = 96MB); Opart (64MB) aliases
  float* big = (float*)alloc((size_t)4 * N * 768 * 4);
  float* Opart = big;
  bf16* hb1 = (bf16*)alloc(ND2);
  bf16* hb2 = (bf16*)alloc(ND2);
  bf16* hbt1 = (bf16*)alloc(ND2);
  bf16* hbt2 = (bf16*)alloc(ND2);
  bf16* A0b1 = (bf16*)alloc((size_t)N * 512 * 2);
  bf16* A0b2 = (bf16*)alloc((size_t)N * 512 * 2);
  bf16* A1b1 = (bf16*)alloc((size_t)N * 512 * 2);
  bf16* A1b2 = (bf16*)alloc((size_t)N * 512 * 2);
  bf16* Wmb = (bf16*)alloc((size_t)256 * 512 * 2);
  bf16* Wihb = (bf16*)alloc((size_t)768 * 512 * 2);
  bf16* Whhb = (bf16*)alloc((size_t)768 * 256 * 2);
  float* ml = (float*)alloc((size_t)8 * N * 2 * 4);
  float* P = (float*)alloc(16 * 256 * 4);
  unsigned* cnt1 = (unsigned*)alloc((size_t)N * 16 * 4);
  unsigned* cnt2 = (unsigned*)alloc((size_t)N * 16 * 4);
  unsigned* deg1 = (unsigned*)alloc((size_t)N * 4);
  unsigned* deg2 = (unsigned*)alloc((size_t)N * 4);
  unsigned* off1 = (unsigned*)alloc((size_t)(N + 1) * 4);
  unsigned* off2 = (unsigned*)alloc((size_t)(N + 1) * 4);
  unsigned* cur1 = (unsigned*)alloc((size_t)N * 4);
  unsigned* cur2 = (unsigned*)alloc((size_t)N * 4);
  int* csr1 = (int*)alloc((size_t)E * 4);
  int* csr2 = (int*)alloc((size_t)E * 4);
  float* gbuf = (float*)alloc((size_t)2 * N * 4);
  float* partb = (float*)alloc((size_t)2 * 32 * 256 * 4);
  float* stats = (float*)alloc(256);

  size_t zbytes = (size_t)((char*)(deg2 + N) - (char*)cnt1);
  hipMemsetAsync(cnt1, 0, zbytes, stream);

  k_gather<<<N, 256, 0, stream>>>(embed, x1, h1);
  k_gather<<<N, 256, 0, stream>>>(embed, x2, h2);
  k_edgeproj<<<16, 256, 0, stream>>>(eemb, Wm, P);
  k_packw<<<256, 256, 0, stream>>>(Wm, Wmb, 768, 512);
  k_packw<<<768, 256, 0, stream>>>(Wih, Wihb, 512, 512);
  k_packw<<<768, 256, 0, stream>>>(Whh, Whhb, 256, 256);
  int eb = (E + 255) / 256;
  k_count<<<eb, 256, 0, stream>>>(ei1, ea1, cnt1, deg1, E);
  k_count<<<eb, 256, 0, stream>>>(ei2, ea2, cnt2, deg2, E);
  k_scan<<<1, 256, 0, stream>>>(deg1, off1, cur1, N);
  k_scan<<<1, 256, 0, stream>>>(deg2, off2, cur2, N);
  k_fill<<<eb, 256, 0, stream>>>(ei1, cur1, csr1, E);
  k_fill<<<eb, 256, 0, stream>>>(ei2, cur2, csr2, E);
  k_cconst<<<N, 256, 0, stream>>>(cnt1, deg1, P, bm, C1);
  k_cconst<<<N, 256, 0, stream>>>(cnt2, deg2, P, bm, C2);

  for (int layer = 0; layer < 3; layer++) {
    k_aggA0<<<dim3(N, 2), 256, 0, stream>>>(h1, h2, csr1, csr2, off1, off2, A0b1, A0b2);
    k_gemmM<<<dim3(N / 128, 2, 2), 256, 0, stream>>>(A0b1, A0b2, Wmb, C1, C2, A1b1, A1b2);
    k_cvt<<<dim3(N / 64, 4, 2), 1024, 0, stream>>>(h1, h2, hb1, hb2, hbt1, hbt2, N);
    k_flash_mfma<<<dim3((N / 128) * 8), 256, 0, stream>>>(hb1, hbt1, hb2, hbt2, Opart, ml, N);
    k_comb<<<dim3(N, 2), 256, 0, stream>>>(Opart, ml, hb1, hb2, A1b1, A1b2, N);
    k_gemmG<<<dim3(N / 128, 6, 4), 256, 0, stream>>>(
        A1b1, A1b2, hb1, hb2, Wihb, Whhb, bih, bhh, big, N);
    k_gru2<<<2 * N, 256, 0, stream>>>(h1, h2, big, N);
  }

  k_gate<<<dim3(N / 4, 2), 256, 0, stream>>>(h1, h2, Wg, bg, gbuf, N);
  k_poolstats<<<2, 256, 0, stream>>>(gbuf, stats, N);
  k_poolpart<<<dim3(32, 2), 256, 0, stream>>>(gbuf, h1, h2, stats, partb, N);
  k_poolfin<<<2, 256, 0, stream>>>(partb, stats, out);
}

// Round 9
// 1678.065 us; speedup vs baseline: 1.2119x; 1.2119x over previous
//
#include <hip/hip_runtime.h>

typedef __bf16 bf16;
typedef __attribute__((ext_vector_type(8))) __bf16 bf16x8;
typedef __attribute__((ext_vector_type(4))) float f32x4;
typedef __attribute__((ext_vector_type(2))) float f32x2;
typedef unsigned int u32;

// ---------------------------------------------------------------------------
// GraphMatchNet: 3x { decomposed message GEMM (bf16 MFMA), dual MFMA flash
// attn (8-wave blocks, 64-key tiles, split-K x4, XCD-colocated), GRU GEMMs }
// ---------------------------------------------------------------------------

__global__ void k_gather(const float* __restrict__ emb, const int* __restrict__ x,
                         float* __restrict__ h) {
  int v = blockIdx.x, d = threadIdx.x;
  h[v * 256 + d] = emb[(size_t)x[v] * 256 + d];
}

__global__ void k_edgeproj(const float* __restrict__ ee, const float* __restrict__ Wm,
                           float* __restrict__ P) {
  __shared__ float row[256];
  int a = blockIdx.x, o = threadIdx.x;
  row[o] = ee[a * 256 + o];
  __syncthreads();
  float s = 0.f;
#pragma unroll 8
  for (int k = 0; k < 256; k++) s += row[k] * Wm[o * 768 + 512 + k];
  P[a * 256 + o] = s;
}

__global__ void k_count(const int* __restrict__ ei, const int* __restrict__ ea,
                        unsigned* __restrict__ cnt, unsigned* __restrict__ deg, int E) {
  int e = blockIdx.x * 256 + threadIdx.x;
  if (e >= E) return;
  int dst = ei[E + e];
  atomicAdd(&cnt[dst * 16 + ea[e]], 1u);
  atomicAdd(&deg[dst], 1u);
}

__global__ void k_scan(const unsigned* __restrict__ deg, unsigned* __restrict__ off,
                       unsigned* __restrict__ cur, int N) {
  __shared__ unsigned part[256];
  int tid = threadIdx.x;
  int per = N >> 8;
  unsigned s = 0;
  for (int i = 0; i < per; i++) s += deg[tid * per + i];
  part[tid] = s;
  __syncthreads();
  if (tid == 0) {
    unsigned run = 0;
    for (int i = 0; i < 256; i++) { unsigned t = part[i]; part[i] = run; run += t; }
  }
  __syncthreads();
  unsigned run = part[tid];
  for (int i = 0; i < per; i++) {
    unsigned dv = deg[tid * per + i];
    off[tid * per + i] = run;
    cur[tid * per + i] = run;
    run += dv;
  }
  if (tid == 255) off[N] = run;
}

__global__ void k_fill(const int* __restrict__ ei, unsigned* __restrict__ cur,
                       int* __restrict__ csr, int E) {
  int e = blockIdx.x * 256 + threadIdx.x;
  if (e >= E) return;
  int dst = ei[E + e];
  unsigned pos = atomicAdd(&cur[dst], 1u);
  csr[pos] = ei[e];  // src
}

__global__ void k_cconst(const unsigned* __restrict__ cnt, const unsigned* __restrict__ deg,
                         const float* __restrict__ P, const float* __restrict__ bm,
                         float* __restrict__ C) {
  int v = blockIdx.x, o = threadIdx.x;
  float s = (float)deg[v] * bm[o];
#pragma unroll
  for (int a = 0; a < 16; a++) s += (float)cnt[v * 16 + a] * P[a * 256 + o];
  C[v * 256 + o] = s;
}

__global__ void k_packw(const float* __restrict__ src, bf16* __restrict__ dst,
                        int srcStride, int K) {
  int o = blockIdx.x;
  for (int k = threadIdx.x; k < K; k += 256)
    dst[(size_t)o * K + k] = (bf16)src[(size_t)o * srcStride + k];
}

// both graphs: A0b[v] = [ bf16(deg*h[v]) | bf16(sum_{src} h[src]) ]
__global__ void k_aggA0(const float* __restrict__ h1, const float* __restrict__ h2,
                        const int* __restrict__ csr1, const int* __restrict__ csr2,
                        const unsigned* __restrict__ off1, const unsigned* __restrict__ off2,
                        bf16* __restrict__ A0b1, bf16* __restrict__ A0b2) {
  int gsel = blockIdx.y;
  const float* h = gsel ? h2 : h1;
  const int* csr = gsel ? csr2 : csr1;
  const unsigned* off = gsel ? off2 : off1;
  bf16* A0b = gsel ? A0b2 : A0b1;
  int v = blockIdx.x, d = threadIdx.x;
  unsigned i0 = off[v], i1 = off[v + 1];
  float s = 0.f;
  for (unsigned i = i0; i < i1; i++) s += h[csr[i] * 256 + d];
  A0b[(size_t)v * 512 + 256 + d] = (bf16)s;
  A0b[(size_t)v * 512 + d] = (bf16)(h[v * 256 + d] * (float)(i1 - i0));
}

// both graphs: h (f32) -> hb (bf16 [N][256]) and hbt (bf16 [256][N])
__global__ void k_cvt(const float* __restrict__ h1, const float* __restrict__ h2,
                      bf16* __restrict__ hb1, bf16* __restrict__ hb2,
                      bf16* __restrict__ hbt1, bf16* __restrict__ hbt2, int N) {
  __shared__ bf16 t[64][68];
  int gsel = blockIdx.z;
  const float* h = gsel ? h2 : h1;
  bf16* hb = gsel ? hb2 : hb1;
  bf16* hbt = gsel ? hbt2 : hbt1;
  int v0 = blockIdx.x * 64, d0 = blockIdx.y * 64;
  int tid = threadIdx.x;
#pragma unroll
  for (int i = 0; i < 4; i++) {
    int e = tid + i * 1024;
    int r = e >> 6, c = e & 63;
    bf16 b = (bf16)h[(size_t)(v0 + r) * 256 + d0 + c];
    hb[(size_t)(v0 + r) * 256 + d0 + c] = b;
    t[r][c] = b;
  }
  __syncthreads();
#pragma unroll
  for (int i = 0; i < 4; i++) {
    int e = tid + i * 1024;
    int dr = e >> 6, vc = e & 63;
    hbt[(size_t)(d0 + dr) * N + v0 + vc] = t[vc][dr];
  }
}

__device__ __forceinline__ void gl2lds16(const bf16* g, bf16* l) {
  __builtin_amdgcn_global_load_lds(
      (const __attribute__((address_space(1))) u32*)(const void*)g,
      (__attribute__((address_space(3))) u32*)(void*)l, 16, 0, 0);
}

// ---------------------------------------------------------------------------
// bf16 MFMA GEMM core (128x128 tile, BK=64, dbuf gl2lds staging).
// ---------------------------------------------------------------------------
template <int MODE>  // 0: +=Cmat, bf16 out stride 512 ; 1: +=bias, f32 out
__device__ __forceinline__ void gemm_body(
    const bf16* __restrict__ A, int sA, const bf16* __restrict__ W,
    const float* __restrict__ biasC, float* __restrict__ outf,
    bf16* __restrict__ outb, int sOut, int K, bf16* lds) {
  int tid = threadIdx.x;
  int w = tid >> 6, l = tid & 63;
  int lane15 = l & 15, g = l >> 4;
  int wr = w >> 1, wc = w & 1;
  int row0 = blockIdx.x * 128, col0 = blockIdx.y * 128;

  const bf16* Abase = A + (size_t)row0 * sA;
  const bf16* Wbase = W + (size_t)col0 * K;
  const int HB = 128 * 64;  // elements per half (A or B) per buffer

  auto stage = [&](int buf, int kt) {
#pragma unroll
    for (int i = 0; i < 4; i++) {
      int c = w * 256 + i * 64 + l;
      int r = c >> 3, c8 = c & 7;
      int sc8 = c8 ^ (r & 7);
      gl2lds16(Abase + (size_t)r * sA + kt + sc8 * 8,
               lds + buf * 2 * HB + (w * 256 + i * 64) * 8);
      gl2lds16(Wbase + (size_t)r * K + kt + sc8 * 8,
               lds + buf * 2 * HB + HB + (w * 256 + i * 64) * 8);
    }
  };

  f32x4 acc[4][4];
#pragma unroll
  for (int a = 0; a < 4; a++)
#pragma unroll
    for (int b = 0; b < 4; b++) acc[a][b] = (f32x4){0.f, 0.f, 0.f, 0.f};

  stage(0, 0);
  __syncthreads();
  int nk = K >> 6;
  for (int t = 0; t < nk; t++) {
    int buf = t & 1;
    if (t + 1 < nk) stage(buf ^ 1, (t + 1) << 6);
    const bf16* La = lds + buf * 2 * HB;
    const bf16* Lb = La + HB;
    bf16x8 af[4][2], bfr[4][2];
#pragma unroll
    for (int mt = 0; mt < 4; mt++) {
      int r = wr * 64 + mt * 16 + lane15;
#pragma unroll
      for (int kk = 0; kk < 2; kk++)
        af[mt][kk] = *(const bf16x8*)(La + r * 64 + (((kk * 4 + g) ^ (r & 7)) * 8));
    }
#pragma unroll
    for (int nt = 0; nt < 4; nt++) {
      int cl = wc * 64 + nt * 16 + lane15;
#pragma unroll
      for (int kk = 0; kk < 2; kk++)
        bfr[nt][kk] = *(const bf16x8*)(Lb + cl * 64 + (((kk * 4 + g) ^ (cl & 7)) * 8));
    }
#pragma unroll
    for (int kk = 0; kk < 2; kk++)
#pragma unroll
      for (int mt = 0; mt < 4; mt++)
#pragma unroll
        for (int nt = 0; nt < 4; nt++)
          acc[mt][nt] =
              __builtin_amdgcn_mfma_f32_16x16x32_bf16(af[mt][kk], bfr[nt][kk], acc[mt][nt], 0, 0, 0);
    __syncthreads();
  }
#pragma unroll
  for (int mt = 0; mt < 4; mt++)
#pragma unroll
    for (int nt = 0; nt < 4; nt++) {
      int col = col0 + wc * 64 + nt * 16 + lane15;
#pragma unroll
      for (int r = 0; r < 4; r++) {
        int row = row0 + wr * 64 + mt * 16 + g * 4 + r;
        float v = acc[mt][nt][r];
        if (MODE == 0)
          outb[(size_t)row * 512 + col] = (bf16)(v + biasC[(size_t)row * 256 + col]);
        else
          outf[(size_t)row * sOut + col] = v + biasC[col];
      }
    }
}

// message GEMM, both graphs (blockIdx.z)
__global__ __launch_bounds__(256, 2) void k_gemmM(
    const bf16* __restrict__ A0b1, const bf16* __restrict__ A0b2,
    const bf16* __restrict__ Wmb, const float* __restrict__ C1,
    const float* __restrict__ C2, bf16* __restrict__ A1b1, bf16* __restrict__ A1b2) {
  __shared__ bf16 lds[2 * 2 * 128 * 64];
  int z = blockIdx.z;
  gemm_body<0>(z ? A0b2 : A0b1, 512, Wmb, z ? C2 : C1, nullptr,
               z ? A1b2 : A1b1, 0, 512, lds);
}

// gate GEMMs: z = graph*2 + (0:GI / 1:GH), both graphs in one launch
__global__ __launch_bounds__(256, 2) void k_gemmG(
    const bf16* __restrict__ A1b1, const bf16* __restrict__ A1b2,
    const bf16* __restrict__ hb1, const bf16* __restrict__ hb2,
    const bf16* __restrict__ Wihb, const bf16* __restrict__ Whhb,
    const float* __restrict__ bih, const float* __restrict__ bhh,
    float* __restrict__ big, int N) {
  __shared__ bf16 lds[2 * 2 * 128 * 64];
  int z = blockIdx.z;
  int graph = z >> 1, mat = z & 1;
  const bf16* A = mat ? (graph ? hb2 : hb1) : (graph ? A1b2 : A1b1);
  float* out = big + (size_t)z * N * 768;
  gemm_body<1>(A, mat ? 256 : 512, mat ? Whhb : Wihb, mat ? bhh : bih,
               out, nullptr, 768, mat ? 256 : 512, lds);
}

// ---------------------------------------------------------------------------
// MFMA flash attention v7: 8 waves x 16 q-rows (128 rows/block), 64-key
// tiles, single 64KB LDS (R3-proven layouts: K XOR 8-slot via gl2lds w16,
// Vt key-perm XOR via VALU staging). launch_bounds(512,4) -> 2 blocks/CU =
// 16 waves/CU (4/SIMD). split-K x4, XCD-colocated (slice = lid%8).
// Plain (non-NT) stores: NT 16B stores write-amplify 4x (R8 evidence).
// ---------------------------------------------------------------------------
__global__ __launch_bounds__(512, 4) void k_flash_mfma(
    const bf16* __restrict__ hb1, const bf16* __restrict__ hbt1,
    const bf16* __restrict__ hb2, const bf16* __restrict__ hbt2,
    float* __restrict__ Opart, float* __restrict__ ml, int N) {
  int lid = blockIdx.x;
  int slice = lid & 7;          // -> XCD (round-robin dispatch)
  int xq = lid >> 3;            // Q-tile index (128 rows)
  int dir = slice & 1, quar = slice >> 1;
  const bf16 *Q, *K, *Kt;
  if (dir == 0) { Q = hb1; K = hb2; Kt = hbt2; }
  else          { Q = hb2; K = hb1; Kt = hbt1; }
  int idx = dir * 4 + quar;
  float* Out = Opart + (size_t)idx * N * 256;
  float* mlp = ml + (size_t)idx * N * 2;

  __shared__ bf16 Klds[64 * 256];   // 32 KB
  __shared__ bf16 Vlds[256 * 64];   // 32 KB
  int tid = threadIdx.x;
  int w = tid >> 6, l = tid & 63;
  int lane15 = l & 15, g = l >> 4;
  int row = xq * 128 + w * 16 + lane15;   // this lane's q-row

  // Q fragments (streaming: non-temporal loads)
  bf16x8 qf[8];
  {
    const bf16* qp = Q + (size_t)row * 256 + g * 8;
#pragma unroll
    for (int kk = 0; kk < 8; kk++)
      qf[kk] = __builtin_nontemporal_load((bf16x8*)(void*)(qp + kk * 32));
  }
  f32x4 Oacc[16];
#pragma unroll
  for (int i = 0; i < 16; i++) Oacc[i] = (f32x4){0.f, 0.f, 0.f, 0.f};
  float m_run = -1e30f, l_run = 0.f;

  int qN = N >> 2;
  int kt0 = quar * qN;
  for (int kt = kt0; kt < kt0 + qN; kt += 64) {
    __syncthreads();
    // stage K tile: gl2lds w16, linear dest, pre-swizzled source 16B-slot
#pragma unroll
    for (int i = 0; i < 4; i++) {
      int c0 = i * 512 + w * 64;
      int c = c0 + l;
      int key = c >> 5, sl = c & 31;
      gl2lds16(K + (size_t)(kt + key) * 256 + ((sl ^ (key & 7)) * 8),
               Klds + (size_t)c0 * 8);
    }
    // stage Vt tile: key-permuted, 8B granules, swizzled 16B-slot ^= d&7
#pragma unroll
    for (int i = 0; i < 8; i++) {
      int c = tid + i * 512;
      int d = c >> 4, j = c & 15;
      float2 v = *(const float2*)(const void*)(Kt + (size_t)d * N + kt + (j & 3) * 16 + (j >> 2) * 4);
      int slot = (j >> 1) ^ (d & 7);
      *(float2*)(void*)(Vlds + d * 64 + slot * 8 + (j & 1) * 4) = v;
    }
    __syncthreads();

    // QK^T (swapped): Sacc[nt][r] = S^T[key=nt*16+4g+r][q=row]
    f32x4 Sacc[4];
#pragma unroll
    for (int i = 0; i < 4; i++) Sacc[i] = (f32x4){0.f, 0.f, 0.f, 0.f};
#pragma unroll
    for (int kk = 0; kk < 8; kk++) {
#pragma unroll
      for (int nt = 0; nt < 4; nt++) {
        int key = nt * 16 + lane15;
        int slot = (kk * 4 + g) ^ (key & 7);
        bf16x8 kf = *(const bf16x8*)(Klds + key * 256 + slot * 8);
        Sacc[nt] = __builtin_amdgcn_mfma_f32_16x16x32_bf16(kf, qf[kk], Sacc[nt], 0, 0, 0);
      }
    }
    // online softmax (16 lane-local vals, xor over lane bits 4,5)
    float tmax = -1e30f;
#pragma unroll
    for (int nt = 0; nt < 4; nt++)
#pragma unroll
      for (int r = 0; r < 4; r++) tmax = fmaxf(tmax, Sacc[nt][r]);
    tmax = fmaxf(tmax, __shfl_xor(tmax, 16));
    tmax = fmaxf(tmax, __shfl_xor(tmax, 32));
    float m_new = fmaxf(m_run, tmax);
    float alpha = __expf(m_run - m_new);
    float ts = 0.f;
#pragma unroll
    for (int nt = 0; nt < 4; nt++)
#pragma unroll
      for (int r = 0; r < 4; r++) {
        float p = __expf(Sacc[nt][r] - m_new);
        Sacc[nt][r] = p;
        ts += p;
      }
    ts += __shfl_xor(ts, 16);
    ts += __shfl_xor(ts, 32);
    bool stable = __all(m_new == m_run);
    if (!stable) {
#pragma unroll
      for (int mt = 0; mt < 16; mt++)
#pragma unroll
        for (int r = 0; r < 4; r++) Oacc[mt][r] *= alpha;
    }
    l_run = l_run * alpha + ts;
    m_run = m_new;
    // P fragments: pbs[s] covers keys s*32..s*32+31 under the key-perm layout
    bf16x8 pbs[2];
#pragma unroll
    for (int s = 0; s < 2; s++)
#pragma unroll
      for (int r = 0; r < 4; r++) {
        pbs[s][r] = (bf16)Sacc[2 * s][r];
        pbs[s][4 + r] = (bf16)Sacc[2 * s + 1][r];
      }
    // PV: O^T += Vt_frag * P_frag
#pragma unroll
    for (int s = 0; s < 2; s++) {
#pragma unroll
      for (int mt = 0; mt < 16; mt++) {
        int d = mt * 16 + lane15;
        int slot = (g * 2 + s) ^ (d & 7);
        bf16x8 vf = *(const bf16x8*)(Vlds + d * 64 + slot * 8);
        Oacc[mt] = __builtin_amdgcn_mfma_f32_16x16x32_bf16(vf, pbs[s], Oacc[mt], 0, 0, 0);
      }
    }
  }
  // epilogue: Oacc[mt][r] = O^T[d = mt*16+4g+r][q = row]; plain stores
  float* orow = Out + (size_t)row * 256 + g * 4;
#pragma unroll
  for (int mt = 0; mt < 16; mt++) {
    f32x4 o = Oacc[mt];
    *(float4*)(orow + mt * 16) = make_float4(o[0], o[1], o[2], o[3]);
  }
  if (g == 0) *(float2*)(mlp + row * 2) = make_float2(m_run, l_run);
}

// merge the four key-quarters; A1b[row][256+d] = bf16(h - att), both graphs
__global__ void k_comb(const float* __restrict__ Opart, const float* __restrict__ ml,
                       const bf16* __restrict__ hb1, const bf16* __restrict__ hb2,
                       bf16* __restrict__ A1b1, bf16* __restrict__ A1b2, int N) {
  int gsel = blockIdx.y;
  const float* Ob = Opart + (size_t)(gsel * 4) * N * 256;
  const float* mlb = ml + (size_t)(gsel * 4) * N * 2;
  const bf16* hb = gsel ? hb2 : hb1;
  bf16* A1b = gsel ? A1b2 : A1b1;
  int row = blockIdx.x, d = threadIdx.x;
  float mx[4], ls[4];
  float m = -1e30f;
#pragma unroll
  for (int q = 0; q < 4; q++) {
    mx[q] = mlb[(size_t)q * N * 2 + row * 2];
    ls[q] = mlb[(size_t)q * N * 2 + row * 2 + 1];
    m = fmaxf(m, mx[q]);
  }
  float denom = 0.f, o = 0.f;
#pragma unroll
  for (int q = 0; q < 4; q++) {
    float a = __expf(mx[q] - m);
    denom += ls[q] * a;
    o += __builtin_nontemporal_load((float*)&Ob[(size_t)q * N * 256 + (size_t)row * 256 + d]) * a;
  }
  o /= denom;
  float hv = (float)hb[(size_t)row * 256 + d];
  A1b[(size_t)row * 512 + 256 + d] = (bf16)(hv - o);
}

// GRU update for both graphs; gi/gh laid out in big[(graph*2 + 0/1)*N*768]
__global__ void k_gru2(float* __restrict__ h1, float* __restrict__ h2,
                       const float* __restrict__ big, int N) {
  int b = blockIdx.x;
  int graph = b >= N;
  int v = graph ? b - N : b;
  int d = threadIdx.x;
  float* h = graph ? h2 : h1;
  const float* gi = big + (size_t)(graph * 2) * N * 768;
  const float* gh = gi + (size_t)N * 768;
  float gir = gi[v * 768 + d], giz = gi[v * 768 + 256 + d], gin = gi[v * 768 + 512 + d];
  float ghr = gh[v * 768 + d], ghz = gh[v * 768 + 256 + d], ghn = gh[v * 768 + 512 + d];
  float r = 1.f / (1.f + __expf(-(gir + ghr)));
  float z = 1.f / (1.f + __expf(-(giz + ghz)));
  float n = tanhf(gin + r * ghn);
  h[v * 256 + d] = (1.f - z) * n + z * h[v * 256 + d];
}

__global__ void k_gate(const float* __restrict__ h1, const float* __restrict__ h2,
                       const float* __restrict__ Wg, const float* __restrict__ bg,
                       float* __restrict__ gbuf, int N) {
  int gsel = blockIdx.y;
  const float* h = gsel ? h2 : h1;
  float* g = gbuf + (size_t)gsel * N;
  int wave = threadIdx.x >> 6, lane = threadIdx.x & 63;
  int v = blockIdx.x * 4 + wave;
  float s = 0.f;
#pragma unroll
  for (int k = lane; k < 256; k += 64) s += h[v * 256 + k] * Wg[k];
#pragma unroll
  for (int sh = 32; sh > 0; sh >>= 1) s += __shfl_xor(s, sh);
  if (lane == 0) g[v] = 1.f / (1.f + __expf(-(s + bg[0])));
}

__global__ void k_poolstats(const float* __restrict__ gbuf, float* __restrict__ stats, int N) {
  __shared__ float red[256];
  int gsel = blockIdx.x;
  const float* g = gbuf + (size_t)gsel * N;
  int tid = threadIdx.x;
  float mx = -1e30f;
  for (int i = tid; i < N; i += 256) mx = fmaxf(mx, g[i]);
  red[tid] = mx;
  __syncthreads();
  for (int s = 128; s > 0; s >>= 1) {
    if (tid < s) red[tid] = fmaxf(red[tid], red[tid + s]);
    __syncthreads();
  }
  float M = red[0];
  __syncthreads();
  float sm = 0.f;
  for (int i = tid; i < N; i += 256) sm += __expf(g[i] - M);
  red[tid] = sm;
  __syncthreads();
  for (int s = 128; s > 0; s >>= 1) {
    if (tid < s) red[tid] += red[tid + s];
    __syncthreads();
  }
  if (tid == 0) { stats[gsel * 2] = M; stats[gsel * 2 + 1] = red[0]; }
}

__global__ void k_poolpart(const float* __restrict__ gbuf, const float* __restrict__ h1,
                           const float* __restrict__ h2, const float* __restrict__ stats,
                           float* __restrict__ part, int N) {
  int gsel = blockIdx.y;
  const float* g = gbuf + (size_t)gsel * N;
  const float* h = gsel ? h2 : h1;
  float* p = part + (size_t)gsel * 32 * 256;
  int c = blockIdx.x, o = threadIdx.x;
  int per = N / 32;
  float M = stats[gsel * 2];
  float s = 0.f;
  for (int v = c * per; v < (c + 1) * per; v++) s += __expf(g[v] - M) * h[v * 256 + o];
  p[c * 256 + o] = s;
}

__global__ void k_poolfin(const float* __restrict__ part, const float* __restrict__ stats,
                          float* __restrict__ out) {
  int gsel = blockIdx.x;
  const float* p = part + (size_t)gsel * 32 * 256;
  int o = threadIdx.x;
  float s = 0.f;
#pragma unroll
  for (int c = 0; c < 32; c++) s += p[c * 256 + o];
  out[gsel * 256 + o] = s / stats[gsel * 2 + 1];
}

extern "C" void kernel_launch(void* const* d_in, const int* in_sizes, int n_in,
                              void* d_out, int out_size, void* d_ws, size_t ws_size,
                              hipStream_t stream) {
  const int* x1 = (const int*)d_in[0];
  const int* x2 = (const int*)d_in[1];
  const int* ei1 = (const int*)d_in[2];
  const int* ei2 = (const int*)d_in[3];
  const int* ea1 = (const int*)d_in[4];
  const int* ea2 = (const int*)d_in[5];
  const float* embed = (const float*)d_in[6];
  const float* eemb = (const float*)d_in[7];
  const float* Wm = (const float*)d_in[8];
  const float* bm = (const float*)d_in[9];
  const float* Wih = (const float*)d_in[10];
  const float* Whh = (const float*)d_in[11];
  const float* bih = (const float*)d_in[12];
  const float* bhh = (const float*)d_in[13];
  const float* Wg = (const float*)d_in[14];
  const float* bg = (const float*)d_in[15];
  const int N = in_sizes[0];   // 8192
  const int E = in_sizes[4];   // 131072
  float* out = (float*)d_out;

  char* ws = (char*)d_ws;
  size_t ofs = 0;
  auto alloc = [&](size_t bytes) -> void* {
    void* p = ws + ofs;
    ofs = (ofs + bytes + 255) & ~(size_t)255;
    return p;
  };
  size_t ND4 = (size_t)N * 256 * 4;
  size_t ND2 = (size_t)N * 256 * 2;
  float* h1 = (float*)alloc(ND4);
  float* h2 = (float*)alloc(ND4);
  float* C1 = (float*)alloc(ND4);
  float* C2 = (float*)alloc(ND4);
  // big region: gi1|gh1|gi2|gh2 (4 * N*768 f32 = 96MB); Opart (64MB) aliases
  float* big = (float*)alloc((size_t)4 * N * 768 * 4);
  float* Opart = big;
  bf16* hb1 = (bf16*)alloc(ND2);
  bf16* hb2 = (bf16*)alloc(ND2);
  bf16* hbt1 = (bf16*)alloc(ND2);
  bf16* hbt2 = (bf16*)alloc(ND2);
  bf16* A0b1 = (bf16*)alloc((size_t)N * 512 * 2);
  bf16* A0b2 = (bf16*)alloc((size_t)N * 512 * 2);
  bf16* A1b1 = (bf16*)alloc((size_t)N * 512 * 2);
  bf16* A1b2 = (bf16*)alloc((size_t)N * 512 * 2);
  bf16* Wmb = (bf16*)alloc((size_t)256 * 512 * 2);
  bf16* Wihb = (bf16*)alloc((size_t)768 * 512 * 2);
  bf16* Whhb = (bf16*)alloc((size_t)768 * 256 * 2);
  float* ml = (float*)alloc((size_t)8 * N * 2 * 4);
  float* P = (float*)alloc(16 * 256 * 4);
  unsigned* cnt1 = (unsigned*)alloc((size_t)N * 16 * 4);
  unsigned* cnt2 = (unsigned*)alloc((size_t)N * 16 * 4);
  unsigned* deg1 = (unsigned*)alloc((size_t)N * 4);
  unsigned* deg2 = (unsigned*)alloc((size_t)N * 4);
  unsigned* off1 = (unsigned*)alloc((size_t)(N + 1) * 4);
  unsigned* off2 = (unsigned*)alloc((size_t)(N + 1) * 4);
  unsigned* cur1 = (unsigned*)alloc((size_t)N * 4);
  unsigned* cur2 = (unsigned*)alloc((size_t)N * 4);
  int* csr1 = (int*)alloc((size_t)E * 4);
  int* csr2 = (int*)alloc((size_t)E * 4);
  float* gbuf = (float*)alloc((size_t)2 * N * 4);
  float* partb = (float*)alloc((size_t)2 * 32 * 256 * 4);
  float* stats = (float*)alloc(256);

  size_t zbytes = (size_t)((char*)(deg2 + N) - (char*)cnt1);
  hipMemsetAsync(cnt1, 0, zbytes, stream);

  k_gather<<<N, 256, 0, stream>>>(embed, x1, h1);
  k_gather<<<N, 256, 0, stream>>>(embed, x2, h2);
  k_edgeproj<<<16, 256, 0, stream>>>(eemb, Wm, P);
  k_packw<<<256, 256, 0, stream>>>(Wm, Wmb, 768, 512);
  k_packw<<<768, 256, 0, stream>>>(Wih, Wihb, 512, 512);
  k_packw<<<768, 256, 0, stream>>>(Whh, Whhb, 256, 256);
  int eb = (E + 255) / 256;
  k_count<<<eb, 256, 0, stream>>>(ei1, ea1, cnt1, deg1, E);
  k_count<<<eb, 256, 0, stream>>>(ei2, ea2, cnt2, deg2, E);
  k_scan<<<1, 256, 0, stream>>>(deg1, off1, cur1, N);
  k_scan<<<1, 256, 0, stream>>>(deg2, off2, cur2, N);
  k_fill<<<eb, 256, 0, stream>>>(ei1, cur1, csr1, E);
  k_fill<<<eb, 256, 0, stream>>>(ei2, cur2, csr2, E);
  k_cconst<<<N, 256, 0, stream>>>(cnt1, deg1, P, bm, C1);
  k_cconst<<<N, 256, 0, stream>>>(cnt2, deg2, P, bm, C2);

  for (int layer = 0; layer < 3; layer++) {
    k_aggA0<<<dim3(N, 2), 256, 0, stream>>>(h1, h2, csr1, csr2, off1, off2, A0b1, A0b2);
    k_gemmM<<<dim3(N / 128, 2, 2), 256, 0, stream>>>(A0b1, A0b2, Wmb, C1, C2, A1b1, A1b2);
    k_cvt<<<dim3(N / 64, 4, 2), 1024, 0, stream>>>(h1, h2, hb1, hb2, hbt1, hbt2, N);
    // flat grid: (N/128)*8 = 512 blocks of 512 threads; slice = lid%8 -> XCD
    k_flash_mfma<<<dim3((N / 128) * 8), 512, 0, stream>>>(hb1, hbt1, hb2, hbt2, Opart, ml, N);
    k_comb<<<dim3(N, 2), 256, 0, stream>>>(Opart, ml, hb1, hb2, A1b1, A1b2, N);
    k_gemmG<<<dim3(N / 128, 6, 4), 256, 0, stream>>>(
        A1b1, A1b2, hb1, hb2, Wihb, Whhb, bih, bhh, big, N);
    k_gru2<<<2 * N, 256, 0, stream>>>(h1, h2, big, N);
  }

  k_gate<<<dim3(N / 4, 2), 256, 0, stream>>>(h1, h2, Wg, bg, gbuf, N);
  k_poolstats<<<2, 256, 0, stream>>>(gbuf, stats, N);
  k_poolpart<<<dim3(32, 2), 256, 0, stream>>>(gbuf, h1, h2, stats, partb, N);
  k_poolfin<<<2, 256, 0, stream>>>(partb, stats, out);
}